// Round 1
// baseline (357.614 us; speedup 1.0000x reference)
//
#include <hip/hip_runtime.h>
#include <hip/hip_bf16.h>

using u16 = unsigned short;

typedef __bf16 bf16x8 __attribute__((ext_vector_type(8)));
typedef float  f32x4  __attribute__((ext_vector_type(4)));

__device__ __forceinline__ float b2f(u16 u) {
  union { unsigned u; float f; } v; v.u = ((unsigned)u) << 16; return v.f;
}
__device__ __forceinline__ u16 f2b(float f) {
  union { float f; unsigned u; } v; v.f = f;
  unsigned r = v.u + 0x7fffu + ((v.u >> 16) & 1u);
  return (u16)(r >> 16);
}

// async global->LDS, 16B per lane. LDS dest must be uniform base + lane*16.
__device__ __forceinline__ void gld_lds16(const void* g, void* l) {
  __builtin_amdgcn_global_load_lds(
      (__attribute__((address_space(1))) void*)(unsigned long long)(g),
      (__attribute__((address_space(3))) void*)(unsigned long long)(l),
      16, 0, 0);
}

// ---------------------------------------------------------------------------
// Generic NT GEMM: C[m,n] = sum_k A[m,k] * B[n,k], bf16 in, fp32 acc.
// Block tile 128x128, 4 waves (2x2), wave = 4x4 of 16x16x32 MFMA, BK=32.
// Batch via blockIdx.z: zb=z/HDIV, zh=z%HDIV; operand offset = zb*s1 + zh*s2.
// EPI: 0 = write bf16; 1 = write fp32; 2 = causal mask (col<=row) -> bf16;
//      3 = divide by den[z*denLd + row] -> bf16; 4 = +bias[col]+resid -> fp32
// ---------------------------------------------------------------------------
template <int EPI>
__global__ __launch_bounds__(256) void gemm_bt(
    const u16* __restrict__ A, int lda, long sA1, long sA2,
    const u16* __restrict__ B, int ldb, long sB1, long sB2,
    void* __restrict__ Cv, int ldc, long sC1, long sC2,
    int K, int HDIV,
    const float* __restrict__ den, int denLd,
    const float* __restrict__ bias, const float* __restrict__ resid) {
  __shared__ __align__(16) u16 lds[8192];  // A: [0,4096) B: [4096,8192) ushorts
  const int t = threadIdx.x;
  const int lane = t & 63;
  const int wave = t >> 6;
  const int wm = wave >> 1, wn = wave & 1;
  const int laneM = lane & 15, quad = lane >> 4;
  const int zb = blockIdx.z / HDIV, zh = blockIdx.z % HDIV;

  const u16* Abase = A + zb * sA1 + zh * sA2 + (long)blockIdx.y * 128 * lda;
  const u16* Bbase = B + zb * sB1 + zh * sB2 + (long)blockIdx.x * 128 * ldb;

  const int rA = t >> 2;        // staging row 0..63 (+64 for second load)
  const int kc = (t & 3) * 8;   // staging k-chunk (8 bf16 = 16B)

  f32x4 acc[4][4];
#pragma unroll
  for (int i = 0; i < 4; ++i)
#pragma unroll
    for (int j = 0; j < 4; ++j) acc[i][j] = (f32x4){0.f, 0.f, 0.f, 0.f};

  const int fragOff = laneM * 32 + quad * 8;  // ushort index within tile

  for (int k0 = 0; k0 < K; k0 += 32) {
    gld_lds16(Abase + (long)rA * lda + k0 + kc, &lds[t * 8]);
    gld_lds16(Abase + (long)(rA + 64) * lda + k0 + kc, &lds[2048 + t * 8]);
    gld_lds16(Bbase + (long)rA * ldb + k0 + kc, &lds[4096 + t * 8]);
    gld_lds16(Bbase + (long)(rA + 64) * ldb + k0 + kc, &lds[6144 + t * 8]);
    __syncthreads();  // drains vmcnt(0): LDS staging complete
    bf16x8 af[4], bfv[4];
#pragma unroll
    for (int i = 0; i < 4; ++i)
      af[i] = *(const bf16x8*)&lds[(wm * 64 + i * 16) * 32 + fragOff];
#pragma unroll
    for (int j = 0; j < 4; ++j)
      bfv[j] = *(const bf16x8*)&lds[4096 + (wn * 64 + j * 16) * 32 + fragOff];
#pragma unroll
    for (int i = 0; i < 4; ++i)
#pragma unroll
      for (int j = 0; j < 4; ++j)
        acc[i][j] = __builtin_amdgcn_mfma_f32_16x16x32_bf16(af[i], bfv[j],
                                                            acc[i][j], 0, 0, 0);
    __syncthreads();  // all waves done reading before next stage
  }

  const long cOff = zb * sC1 + zh * sC2;
  const int rowB = blockIdx.y * 128 + wm * 64;
  const int colB = blockIdx.x * 128 + wn * 64;
#pragma unroll
  for (int i = 0; i < 4; ++i) {
#pragma unroll
    for (int j = 0; j < 4; ++j) {
#pragma unroll
      for (int r = 0; r < 4; ++r) {
        const int row = rowB + i * 16 + quad * 4 + r;  // within-batch row
        const int col = colB + j * 16 + laneM;         // within-batch col
        const long idx = cOff + (long)row * ldc + col;
        float v = acc[i][j][r];
        if (EPI == 0) {
          ((u16*)Cv)[idx] = f2b(v);
        } else if (EPI == 1) {
          ((float*)Cv)[idx] = v;
        } else if (EPI == 2) {
          ((u16*)Cv)[idx] = f2b(col <= row ? v : 0.0f);
        } else if (EPI == 3) {
          ((u16*)Cv)[idx] = f2b(v / den[(long)blockIdx.z * denLd + row]);
        } else {
          ((float*)Cv)[idx] = v + bias[col] + resid[(long)row * ldc + col];
        }
      }
    }
  }
}

// ---------------------------------------------------------------------------
// Convert 7 fp32 2048x2048 tensors -> bf16, dsts contiguous from dst base.
// ---------------------------------------------------------------------------
__global__ __launch_bounds__(256) void convert7(
    const float* __restrict__ s0, const float* __restrict__ s1,
    const float* __restrict__ s2, const float* __restrict__ s3,
    const float* __restrict__ s4, const float* __restrict__ s5,
    const float* __restrict__ s6, u16* __restrict__ dst) {
  long idx = (long)blockIdx.x * 256 + threadIdx.x;  // 0 .. 7*1048576-1
  int seg = (int)(idx >> 20);
  long off = (idx & 1048575) << 2;
  const float* s;
  switch (seg) {
    case 0: s = s0; break; case 1: s = s1; break; case 2: s = s2; break;
    case 3: s = s3; break; case 4: s = s4; break; case 5: s = s5; break;
    default: s = s6;
  }
  float4 v = *(const float4*)(s + off);
  ushort4 o;
  o.x = f2b(v.x); o.y = f2b(v.y); o.z = f2b(v.z); o.w = f2b(v.w);
  *(ushort4*)(dst + (long)seg * 4194304 + off) = o;
}

// ---------------------------------------------------------------------------
// partial[h,chunk,m] = sum over 128 (b,l) rows of kv[b,h,l,m]
// ---------------------------------------------------------------------------
__global__ __launch_bounds__(256) void kv_mean_partial(
    const float* __restrict__ kv, float* __restrict__ part) {
  int h = blockIdx.x, chunk = blockIdx.y, m = threadIdx.x;
  float acc = 0.f;
  for (int g = chunk * 128; g < chunk * 128 + 128; ++g) {
    int b = g >> 8, l = g & 255;
    acc += kv[(((long)(b * 8 + h) * 256) + l) * 256 + m];
  }
  part[(h * 16 + chunk) * 256 + m] = acc;
}

// cs_seq[h,m]: scan over heads collecting the PRE-update carry.
__global__ __launch_bounds__(256) void cs_kernel(
    const float* __restrict__ part, float* __restrict__ cs,
    const float* __restrict__ alphaP, const float* __restrict__ betaP) {
  int m = threadIdx.x;
  float alpha = *alphaP, beta = *betaP;
  float c = 0.f;
  for (int h = 0; h < 8; ++h) {
    cs[h * 256 + m] = c;
    float s = 0.f;
    for (int ch = 0; ch < 16; ++ch) s += part[(h * 16 + ch) * 256 + m];
    c = beta * c + alpha * (s * (1.0f / 2048.0f));
  }
}

// pq = phi(Q * (cs + alpha*(kv - cs))), pk = phi(K); phi(x)=x>0?x+1:exp(x)
__global__ __launch_bounds__(256) void pqpk_kernel(
    const u16* __restrict__ Qp, const u16* __restrict__ Kp,
    const float* __restrict__ kv, const float* __restrict__ cs,
    const float* __restrict__ alphaP, u16* __restrict__ pq,
    u16* __restrict__ pk) {
  long idx = (long)blockIdx.x * 256 + threadIdx.x;  // (b,h,l,d) packed
  int d = idx & 255, l = (int)((idx >> 8) & 255), h = (int)((idx >> 16) & 7),
      b = (int)(idx >> 19);
  float alpha = *alphaP;
  long pidx = ((long)(b * 256 + l)) * 2048 + h * 256 + d;
  float Qv = b2f(Qp[pidx]);
  float kvv = kv[idx];  // kv layout (b,h,l,m) == idx packing
  float csv = cs[h * 256 + d];
  float qm = Qv * (csv + alpha * (kvv - csv));
  pq[idx] = f2b(qm > 0.f ? qm + 1.f : expf(qm));
  float Kv = b2f(Kp[pidx]);
  pk[idx] = f2b(Kv > 0.f ? Kv + 1.f : expf(Kv));
}

// den[row] = max(rowsum of masked A, 1e-8); one wave per row of 256.
__global__ __launch_bounds__(256) void den_kernel(const u16* __restrict__ Ab,
                                                  float* __restrict__ den) {
  int wave = threadIdx.x >> 6, lane = threadIdx.x & 63;
  int row = blockIdx.x * 4 + wave;  // 0..16383
  ushort4 v = *(const ushort4*)(Ab + (long)row * 256 + lane * 4);
  float s = b2f(v.x) + b2f(v.y) + b2f(v.z) + b2f(v.w);
  for (int o = 32; o; o >>= 1) s += __shfl_xor(s, o);
  if (lane == 0) den[row] = fmaxf(s, 1e-8f);
}

// Vt[b,h,d,j] = V[b*256+j, h*256+d]  (per-(b,h) 256x256 transpose)
__global__ __launch_bounds__(256) void vtrans_kernel(const u16* __restrict__ Vp,
                                                     u16* __restrict__ Vt) {
  __shared__ u16 tile[32][33];
  int z = blockIdx.z, b = z >> 3, h = z & 7;
  int jT = blockIdx.x * 32, dT = blockIdx.y * 32;
  int tx = threadIdx.x, ty = threadIdx.y;  // (32, 8)
#pragma unroll
  for (int ii = 0; ii < 4; ++ii) {
    int j = jT + ty + ii * 8, d = dT + tx;
    tile[ty + ii * 8][tx] = Vp[(long)(b * 256 + j) * 2048 + h * 256 + d];
  }
  __syncthreads();
#pragma unroll
  for (int ii = 0; ii < 4; ++ii) {
    int d = dT + ty + ii * 8, j = jT + tx;
    Vt[(long)z * 65536 + d * 256 + j] = tile[tx][ty + ii * 8];
  }
}

// LayerNorm over rows of 2048.
__global__ __launch_bounds__(256) void ln_kernel(
    const float* __restrict__ x, const float* __restrict__ g,
    const float* __restrict__ bb, float* __restrict__ out) {
  int row = blockIdx.x, t = threadIdx.x;
  const float4* xr = (const float4*)(x + (long)row * 2048);
  float4 v0 = xr[t], v1 = xr[t + 256];
  float s = v0.x + v0.y + v0.z + v0.w + v1.x + v1.y + v1.z + v1.w;
  float ss = v0.x * v0.x + v0.y * v0.y + v0.z * v0.z + v0.w * v0.w +
             v1.x * v1.x + v1.y * v1.y + v1.z * v1.z + v1.w * v1.w;
  for (int o = 32; o; o >>= 1) { s += __shfl_xor(s, o); ss += __shfl_xor(ss, o); }
  __shared__ float a1[4], a2[4];
  int wave = t >> 6, lane = t & 63;
  if (lane == 0) { a1[wave] = s; a2[wave] = ss; }
  __syncthreads();
  s = a1[0] + a1[1] + a1[2] + a1[3];
  ss = a2[0] + a2[1] + a2[2] + a2[3];
  float mu = s * (1.f / 2048.f);
  float var = ss * (1.f / 2048.f) - mu * mu;
  float rstd = rsqrtf(var + 1e-5f);
  const float4* g4 = (const float4*)g;
  const float4* b4 = (const float4*)bb;
  float4* orow = (float4*)(out + (long)row * 2048);
  float4 gg = g4[t], bv = b4[t], r;
  r.x = (v0.x - mu) * rstd * gg.x + bv.x;
  r.y = (v0.y - mu) * rstd * gg.y + bv.y;
  r.z = (v0.z - mu) * rstd * gg.z + bv.z;
  r.w = (v0.w - mu) * rstd * gg.w + bv.w;
  orow[t] = r;
  gg = g4[t + 256]; bv = b4[t + 256];
  r.x = (v1.x - mu) * rstd * gg.x + bv.x;
  r.y = (v1.y - mu) * rstd * gg.y + bv.y;
  r.z = (v1.z - mu) * rstd * gg.z + bv.z;
  r.w = (v1.w - mu) * rstd * gg.w + bv.w;
  orow[t + 256] = r;
}

extern "C" void kernel_launch(void* const* d_in, const int* in_sizes, int n_in,
                              void* d_out, int out_size, void* d_ws,
                              size_t ws_size, hipStream_t stream) {
  const float* query = (const float*)d_in[0];
  const float* key = (const float*)d_in[1];
  const float* value = (const float*)d_in[2];
  const float* Wq = (const float*)d_in[3];
  const float* Wk = (const float*)d_in[4];
  const float* Wv = (const float*)d_in[5];
  const float* Wo = (const float*)d_in[6];
  const float* bo = (const float*)d_in[7];
  const float* ln_g = (const float*)d_in[8];
  const float* ln_b = (const float*)d_in[9];
  const float* alphaP = (const float*)d_in[10];
  const float* betaP = (const float*)d_in[11];

  char* ws = (char*)d_ws;
  const long SZ = 8388608;  // bytes of one 2048x2048 bf16 tensor
  u16* qb = (u16*)(ws);                // q,k,v bf16 (3*SZ)
  u16* Wb = (u16*)(ws + 3 * SZ);       // Wq,Wk,Wv,Wo bf16 (4*SZ)
  u16* Qp = (u16*)(ws + 7 * SZ);       // Q,K,V projections bf16 (3*SZ)
  float* kvf = (float*)(ws + 10 * SZ); // kv fp32 (2*SZ); later aliased by Ab
  u16* pq = (u16*)(ws + 12 * SZ);      // (SZ)
  u16* pk = (u16*)(ws + 13 * SZ);      // (SZ)
  u16* Vt = (u16*)(ws + 14 * SZ);      // (SZ)
  u16* attnb = (u16*)(ws + 15 * SZ);   // (SZ)
  u16* Ab = (u16*)(ws + 10 * SZ);      // aliases kvf (dead after pqpk)
  float* x = (float*)(ws + 12 * SZ);   // aliases pq/pk (dead after A GEMM)
  float* den = (float*)(ws + 16 * SZ);             // 64 KB
  float* part = (float*)(ws + 16 * SZ + 65536);    // 16 KB
  float* cs = (float*)(ws + 16 * SZ + 65536 + 16384);  // 8 KB

  u16* Kp = Qp + 4194304;
  u16* Vp = Qp + 8388608;
  u16* Wob = Wb + 3 * 4194304;

  // 1. fp32 -> bf16 converts (7 tensors)
  convert7<<<28672, 256, 0, stream>>>(query, key, value, Wq, Wk, Wv, Wo, qb);

  // 2. Q/K/V projections: z=0..2 batched, C[m,n] = sum_k x[m,k] W[n,k]
  gemm_bt<0><<<dim3(16, 16, 3), 256, 0, stream>>>(
      qb, 2048, 4194304L, 0L, Wb, 2048, 4194304L, 0L, (void*)Qp, 2048,
      4194304L, 0L, 2048, 1, nullptr, 0, nullptr, nullptr);

  // 3. kv[b,h,l,m] = sum_d K[b,h,l,d] V[b,h,m,d]  (64 batches, fp32 out)
  gemm_bt<1><<<dim3(2, 2, 64), 256, 0, stream>>>(
      Kp, 2048, 524288L, 256L, Vp, 2048, 524288L, 256L, (void*)kvf, 256,
      524288L, 65536L, 256, 8, nullptr, 0, nullptr, nullptr);

  // 4-5. head-means of kv + cs scan over heads
  kv_mean_partial<<<dim3(8, 16), 256, 0, stream>>>(kvf, part);
  cs_kernel<<<1, 256, 0, stream>>>(part, cs, alphaP, betaP);

  // 6. pq = phi(Q*(cs+alpha*(kv-cs))), pk = phi(K)
  pqpk_kernel<<<16384, 256, 0, stream>>>(Qp, Kp, kvf, cs, alphaP, pq, pk);

  // 7. A = pq @ pk^T, causal-masked, bf16 (overwrites kv region)
  gemm_bt<2><<<dim3(2, 2, 64), 256, 0, stream>>>(
      pq, 256, 524288L, 65536L, pk, 256, 524288L, 65536L, (void*)Ab, 256,
      524288L, 65536L, 256, 8, nullptr, 0, nullptr, nullptr);

  // 8. den = rowsum(A) (mask already applied), clamped
  den_kernel<<<4096, 256, 0, stream>>>(Ab, den);

  // 9. V transpose per (b,h): Vt[d,j] = V[j,d]
  vtrans_kernel<<<dim3(8, 8, 64), dim3(32, 8), 0, stream>>>(Vp, Vt);

  // 10. attn = (A @ V) / den, written into (B*L, D) layout at col h*256
  gemm_bt<3><<<dim3(2, 2, 64), 256, 0, stream>>>(
      Ab, 256, 524288L, 65536L, Vt, 256, 524288L, 65536L, (void*)attnb, 2048,
      524288L, 256L, 256, 8, den, 256, nullptr, nullptr);

  // 11. x = attn @ Wo^T + bo + query (fp32)
  gemm_bt<4><<<dim3(16, 16, 1), 256, 0, stream>>>(
      attnb, 2048, 0L, 0L, Wob, 2048, 0L, 0L, (void*)x, 2048, 0L, 0L, 2048, 1,
      nullptr, 0, bo, query);

  // 12. LayerNorm -> d_out
  ln_kernel<<<2048, 256, 0, stream>>>(x, ln_g, ln_b, (float*)d_out);
}

// Round 2
// 350.548 us; speedup vs baseline: 1.0202x; 1.0202x over previous
//
#include <hip/hip_runtime.h>
#include <hip/hip_bf16.h>

using u16 = unsigned short;

typedef __bf16 bf16x8 __attribute__((ext_vector_type(8)));
typedef float  f32x4  __attribute__((ext_vector_type(4)));

__device__ __forceinline__ float b2f(u16 u) {
  union { unsigned u; float f; } v; v.u = ((unsigned)u) << 16; return v.f;
}
__device__ __forceinline__ u16 f2b(float f) {
  union { float f; unsigned u; } v; v.f = f;
  unsigned r = v.u + 0x7fffu + ((v.u >> 16) & 1u);
  return (u16)(r >> 16);
}

// async global->LDS, 16B per lane. LDS dest must be uniform base + lane*16.
__device__ __forceinline__ void gld_lds16(const void* g, void* l) {
  __builtin_amdgcn_global_load_lds(
      (__attribute__((address_space(1))) void*)(unsigned long long)(g),
      (__attribute__((address_space(3))) void*)(unsigned long long)(l),
      16, 0, 0);
}

// ---------------------------------------------------------------------------
// Generic NT GEMM: C[m,n] = sum_k A[m,k] * B[n,k], bf16 in, fp32 acc.
// Block tile 128x128, 4 waves (2x2), wave = 4x4 of 16x16x32 MFMA, BK=32.
// LDS k-chunk XOR swizzle: chunk c of row r stored at granule r*4+(c^((r>>1)&3))
// so ds_read_b128 fragment reads spread over all 8 granule-positions (2-way
// bank aliasing = free). Staging picks the permuted global chunk per thread.
// Batch via blockIdx.z: zb=z/HDIV, zh=z%HDIV; operand offset = zb*s1 + zh*s2.
// EPI: 0 = write bf16; 1 = write fp32;
//      2 = causal A-GEMM: grid x in {0,1,2} remapped to (x,y) in
//          {(0,0),(0,1),(1,1)}, mask col<=row -> bf16;
//      3 = A@V: K clamped to (y+1)*128 (A cols > that are zero/unwritten),
//          divide by den[z*denLd + row] -> bf16;
//      4 = +bias[col]+resid -> fp32
// ---------------------------------------------------------------------------
template <int EPI>
__global__ __launch_bounds__(256) void gemm_bt(
    const u16* __restrict__ A, int lda, long sA1, long sA2,
    const u16* __restrict__ B, int ldb, long sB1, long sB2,
    void* __restrict__ Cv, int ldc, long sC1, long sC2,
    int K, int HDIV,
    const float* __restrict__ den, int denLd,
    const float* __restrict__ bias, const float* __restrict__ resid) {
  __shared__ __align__(16) u16 lds[8192];  // A: [0,4096) B: [4096,8192) ushorts
  const int t = threadIdx.x;
  const int lane = t & 63;
  const int wave = t >> 6;
  const int wm = wave >> 1, wn = wave & 1;
  const int laneM = lane & 15, quad = lane >> 4;
  const int zb = blockIdx.z / HDIV, zh = blockIdx.z % HDIV;

  int bx = blockIdx.x, by = blockIdx.y;
  if (EPI == 2) { by = (bx >= 1) ? 1 : 0; bx = (bx == 2) ? 1 : 0; }
  const int kEnd = (EPI == 3) ? ((by + 1) * 128 < K ? (by + 1) * 128 : K) : K;

  const u16* Abase = A + zb * sA1 + zh * sA2 + (long)by * 128 * lda;
  const u16* Bbase = B + zb * sB1 + zh * sB2 + (long)bx * 128 * ldb;

  const int rA = t >> 2;  // staging row 0..63 (+64 for second load)
  // swizzled source chunk: granule (t&3) holds global chunk (t&3)^((rA>>1)&3)
  const int kc = (((t & 3) ^ ((rA >> 1) & 3)) * 8);  // same for row rA+64

  f32x4 acc[4][4];
#pragma unroll
  for (int i = 0; i < 4; ++i)
#pragma unroll
    for (int j = 0; j < 4; ++j) acc[i][j] = (f32x4){0.f, 0.f, 0.f, 0.f};

  // fragment read offset with matching XOR swizzle (base rows are mult of 16,
  // so (row>>1)&3 == (laneM>>1)&3 -- lane-constant across i/j)
  const int fragOff = laneM * 32 + ((quad ^ ((laneM >> 1) & 3)) * 8);

  for (int k0 = 0; k0 < kEnd; k0 += 32) {
    gld_lds16(Abase + (long)rA * lda + k0 + kc, &lds[t * 8]);
    gld_lds16(Abase + (long)(rA + 64) * lda + k0 + kc, &lds[2048 + t * 8]);
    gld_lds16(Bbase + (long)rA * ldb + k0 + kc, &lds[4096 + t * 8]);
    gld_lds16(Bbase + (long)(rA + 64) * ldb + k0 + kc, &lds[6144 + t * 8]);
    __syncthreads();  // drains vmcnt(0): LDS staging complete
    bf16x8 af[4], bfv[4];
#pragma unroll
    for (int i = 0; i < 4; ++i)
      af[i] = *(const bf16x8*)&lds[(wm * 64 + i * 16) * 32 + fragOff];
#pragma unroll
    for (int j = 0; j < 4; ++j)
      bfv[j] = *(const bf16x8*)&lds[4096 + (wn * 64 + j * 16) * 32 + fragOff];
#pragma unroll
    for (int i = 0; i < 4; ++i)
#pragma unroll
      for (int j = 0; j < 4; ++j)
        acc[i][j] = __builtin_amdgcn_mfma_f32_16x16x32_bf16(af[i], bfv[j],
                                                            acc[i][j], 0, 0, 0);
    __syncthreads();  // all waves done reading before next stage
  }

  const long cOff = zb * sC1 + zh * sC2;
  const int rowB = by * 128 + wm * 64;
  const int colB = bx * 128 + wn * 64;
#pragma unroll
  for (int i = 0; i < 4; ++i) {
#pragma unroll
    for (int j = 0; j < 4; ++j) {
#pragma unroll
      for (int r = 0; r < 4; ++r) {
        const int row = rowB + i * 16 + quad * 4 + r;  // within-batch row
        const int col = colB + j * 16 + laneM;         // within-batch col
        const long idx = cOff + (long)row * ldc + col;
        float v = acc[i][j][r];
        if (EPI == 0) {
          ((u16*)Cv)[idx] = f2b(v);
        } else if (EPI == 1) {
          ((float*)Cv)[idx] = v;
        } else if (EPI == 2) {
          ((u16*)Cv)[idx] = f2b(col <= row ? v : 0.0f);
        } else if (EPI == 3) {
          ((u16*)Cv)[idx] = f2b(v / den[(long)blockIdx.z * denLd + row]);
        } else {
          ((float*)Cv)[idx] = v + bias[col] + resid[(long)row * ldc + col];
        }
      }
    }
  }
}

// ---------------------------------------------------------------------------
// Convert 7 fp32 2048x2048 tensors -> bf16, dsts contiguous from dst base.
// ---------------------------------------------------------------------------
__global__ __launch_bounds__(256) void convert7(
    const float* __restrict__ s0, const float* __restrict__ s1,
    const float* __restrict__ s2, const float* __restrict__ s3,
    const float* __restrict__ s4, const float* __restrict__ s5,
    const float* __restrict__ s6, u16* __restrict__ dst) {
  long idx = (long)blockIdx.x * 256 + threadIdx.x;  // 0 .. 7*1048576-1
  int seg = (int)(idx >> 20);
  long off = (idx & 1048575) << 2;
  const float* s;
  switch (seg) {
    case 0: s = s0; break; case 1: s = s1; break; case 2: s = s2; break;
    case 3: s = s3; break; case 4: s = s4; break; case 5: s = s5; break;
    default: s = s6;
  }
  float4 v = *(const float4*)(s + off);
  ushort4 o;
  o.x = f2b(v.x); o.y = f2b(v.y); o.z = f2b(v.z); o.w = f2b(v.w);
  *(ushort4*)(dst + (long)seg * 4194304 + off) = o;
}

// ---------------------------------------------------------------------------
// partial[h,chunk,m] = sum over 128 (b,l) rows of kv[b,h,l,m]
// ---------------------------------------------------------------------------
__global__ __launch_bounds__(256) void kv_mean_partial(
    const float* __restrict__ kv, float* __restrict__ part) {
  int h = blockIdx.x, chunk = blockIdx.y, m = threadIdx.x;
  float acc = 0.f;
  for (int g = chunk * 128; g < chunk * 128 + 128; ++g) {
    int b = g >> 8, l = g & 255;
    acc += kv[(((long)(b * 8 + h) * 256) + l) * 256 + m];
  }
  part[(h * 16 + chunk) * 256 + m] = acc;
}

// cs_seq[h,m]: scan over heads collecting the PRE-update carry.
__global__ __launch_bounds__(256) void cs_kernel(
    const float* __restrict__ part, float* __restrict__ cs,
    const float* __restrict__ alphaP, const float* __restrict__ betaP) {
  int m = threadIdx.x;
  float alpha = *alphaP, beta = *betaP;
  float c = 0.f;
  for (int h = 0; h < 8; ++h) {
    cs[h * 256 + m] = c;
    float s = 0.f;
    for (int ch = 0; ch < 16; ++ch) s += part[(h * 16 + ch) * 256 + m];
    c = beta * c + alpha * (s * (1.0f / 2048.0f));
  }
}

// pq = phi(Q * (cs + alpha*(kv - cs))), pk = phi(K); phi(x)=x>0?x+1:exp(x)
__global__ __launch_bounds__(256) void pqpk_kernel(
    const u16* __restrict__ Qp, const u16* __restrict__ Kp,
    const float* __restrict__ kv, const float* __restrict__ cs,
    const float* __restrict__ alphaP, u16* __restrict__ pq,
    u16* __restrict__ pk) {
  long idx = (long)blockIdx.x * 256 + threadIdx.x;  // (b,h,l,d) packed
  int d = idx & 255, l = (int)((idx >> 8) & 255), h = (int)((idx >> 16) & 7),
      b = (int)(idx >> 19);
  float alpha = *alphaP;
  long pidx = ((long)(b * 256 + l)) * 2048 + h * 256 + d;
  float Qv = b2f(Qp[pidx]);
  float kvv = kv[idx];  // kv layout (b,h,l,m) == idx packing
  float csv = cs[h * 256 + d];
  float qm = Qv * (csv + alpha * (kvv - csv));
  pq[idx] = f2b(qm > 0.f ? qm + 1.f : expf(qm));
  float Kv = b2f(Kp[pidx]);
  pk[idx] = f2b(Kv > 0.f ? Kv + 1.f : expf(Kv));
}

// den[row] = max(sum_{j<=row%256} A[row,j], 1e-8); one wave per row of 256.
// Mask j<=row is required: the fully-masked A block (cols 128..255 of rows
// 0..127) is never written (poison) now that the A-GEMM skips it.
__global__ __launch_bounds__(256) void den_kernel(const u16* __restrict__ Ab,
                                                  float* __restrict__ den) {
  int wave = threadIdx.x >> 6, lane = threadIdx.x & 63;
  int row = blockIdx.x * 4 + wave;  // 0..16383
  int rloc = row & 255;
  ushort4 v = *(const ushort4*)(Ab + (long)row * 256 + lane * 4);
  int j = lane * 4;
  float s = (j <= rloc ? b2f(v.x) : 0.f) + (j + 1 <= rloc ? b2f(v.y) : 0.f) +
            (j + 2 <= rloc ? b2f(v.z) : 0.f) + (j + 3 <= rloc ? b2f(v.w) : 0.f);
  for (int o = 32; o; o >>= 1) s += __shfl_xor(s, o);
  if (lane == 0) den[row] = fmaxf(s, 1e-8f);
}

// Vt[b,h,d,j] = V[b*256+j, h*256+d]  (per-(b,h) 256x256 transpose)
__global__ __launch_bounds__(256) void vtrans_kernel(const u16* __restrict__ Vp,
                                                     u16* __restrict__ Vt) {
  __shared__ u16 tile[32][33];
  int z = blockIdx.z, b = z >> 3, h = z & 7;
  int jT = blockIdx.x * 32, dT = blockIdx.y * 32;
  int tx = threadIdx.x, ty = threadIdx.y;  // (32, 8)
#pragma unroll
  for (int ii = 0; ii < 4; ++ii) {
    int j = jT + ty + ii * 8, d = dT + tx;
    tile[ty + ii * 8][tx] = Vp[(long)(b * 256 + j) * 2048 + h * 256 + d];
  }
  __syncthreads();
#pragma unroll
  for (int ii = 0; ii < 4; ++ii) {
    int d = dT + ty + ii * 8, j = jT + tx;
    Vt[(long)z * 65536 + d * 256 + j] = tile[tx][ty + ii * 8];
  }
}

// LayerNorm over rows of 2048.
__global__ __launch_bounds__(256) void ln_kernel(
    const float* __restrict__ x, const float* __restrict__ g,
    const float* __restrict__ bb, float* __restrict__ out) {
  int row = blockIdx.x, t = threadIdx.x;
  const float4* xr = (const float4*)(x + (long)row * 2048);
  float4 v0 = xr[t], v1 = xr[t + 256];
  float s = v0.x + v0.y + v0.z + v0.w + v1.x + v1.y + v1.z + v1.w;
  float ss = v0.x * v0.x + v0.y * v0.y + v0.z * v0.z + v0.w * v0.w +
             v1.x * v1.x + v1.y * v1.y + v1.z * v1.z + v1.w * v1.w;
  for (int o = 32; o; o >>= 1) { s += __shfl_xor(s, o); ss += __shfl_xor(ss, o); }
  __shared__ float a1[4], a2[4];
  int wave = t >> 6, lane = t & 63;
  if (lane == 0) { a1[wave] = s; a2[wave] = ss; }
  __syncthreads();
  s = a1[0] + a1[1] + a1[2] + a1[3];
  ss = a2[0] + a2[1] + a2[2] + a2[3];
  float mu = s * (1.f / 2048.f);
  float var = ss * (1.f / 2048.f) - mu * mu;
  float rstd = rsqrtf(var + 1e-5f);
  const float4* g4 = (const float4*)g;
  const float4* b4 = (const float4*)bb;
  float4* orow = (float4*)(out + (long)row * 2048);
  float4 gg = g4[t], bv = b4[t], r;
  r.x = (v0.x - mu) * rstd * gg.x + bv.x;
  r.y = (v0.y - mu) * rstd * gg.y + bv.y;
  r.z = (v0.z - mu) * rstd * gg.z + bv.z;
  r.w = (v0.w - mu) * rstd * gg.w + bv.w;
  orow[t] = r;
  gg = g4[t + 256]; bv = b4[t + 256];
  r.x = (v1.x - mu) * rstd * gg.x + bv.x;
  r.y = (v1.y - mu) * rstd * gg.y + bv.y;
  r.z = (v1.z - mu) * rstd * gg.z + bv.z;
  r.w = (v1.w - mu) * rstd * gg.w + bv.w;
  orow[t + 256] = r;
}

extern "C" void kernel_launch(void* const* d_in, const int* in_sizes, int n_in,
                              void* d_out, int out_size, void* d_ws,
                              size_t ws_size, hipStream_t stream) {
  const float* query = (const float*)d_in[0];
  const float* key = (const float*)d_in[1];
  const float* value = (const float*)d_in[2];
  const float* Wq = (const float*)d_in[3];
  const float* Wk = (const float*)d_in[4];
  const float* Wv = (const float*)d_in[5];
  const float* Wo = (const float*)d_in[6];
  const float* bo = (const float*)d_in[7];
  const float* ln_g = (const float*)d_in[8];
  const float* ln_b = (const float*)d_in[9];
  const float* alphaP = (const float*)d_in[10];
  const float* betaP = (const float*)d_in[11];

  char* ws = (char*)d_ws;
  const long SZ = 8388608;  // bytes of one 2048x2048 bf16 tensor
  u16* qb = (u16*)(ws);                // q,k,v bf16 (3*SZ)
  u16* Wb = (u16*)(ws + 3 * SZ);       // Wq,Wk,Wv,Wo bf16 (4*SZ)
  u16* Qp = (u16*)(ws + 7 * SZ);       // Q,K,V projections bf16 (3*SZ)
  float* kvf = (float*)(ws + 10 * SZ); // kv fp32 (2*SZ); later aliased by Ab
  u16* pq = (u16*)(ws + 12 * SZ);      // (SZ)
  u16* pk = (u16*)(ws + 13 * SZ);      // (SZ)
  u16* Vt = (u16*)(ws + 14 * SZ);      // (SZ)
  u16* attnb = (u16*)(ws + 15 * SZ);   // (SZ)
  u16* Ab = (u16*)(ws + 10 * SZ);      // aliases kvf (dead after pqpk)
  float* x = (float*)(ws + 12 * SZ);   // aliases pq/pk (dead after A GEMM)
  float* den = (float*)(ws + 16 * SZ);             // 64 KB
  float* part = (float*)(ws + 16 * SZ + 65536);    // 16 KB
  float* cs = (float*)(ws + 16 * SZ + 65536 + 16384);  // 8 KB

  u16* Kp = Qp + 4194304;
  u16* Vp = Qp + 8388608;
  u16* Wob = Wb + 3 * 4194304;

  // 1. fp32 -> bf16 converts (7 tensors)
  convert7<<<28672, 256, 0, stream>>>(query, key, value, Wq, Wk, Wv, Wo, qb);

  // 2. Q/K/V projections: z=0..2 batched, C[m,n] = sum_k x[m,k] W[n,k]
  gemm_bt<0><<<dim3(16, 16, 3), 256, 0, stream>>>(
      qb, 2048, 4194304L, 0L, Wb, 2048, 4194304L, 0L, (void*)Qp, 2048,
      4194304L, 0L, 2048, 1, nullptr, 0, nullptr, nullptr);

  // 3. kv[b,h,l,m] = sum_d K[b,h,l,d] V[b,h,m,d]  (64 batches, fp32 out)
  gemm_bt<1><<<dim3(2, 2, 64), 256, 0, stream>>>(
      Kp, 2048, 524288L, 256L, Vp, 2048, 524288L, 256L, (void*)kvf, 256,
      524288L, 65536L, 256, 8, nullptr, 0, nullptr, nullptr);

  // 4-5. head-means of kv + cs scan over heads
  kv_mean_partial<<<dim3(8, 16), 256, 0, stream>>>(kvf, part);
  cs_kernel<<<1, 256, 0, stream>>>(part, cs, alphaP, betaP);

  // 6. pq = phi(Q*(cs+alpha*(kv-cs))), pk = phi(K)
  pqpk_kernel<<<16384, 256, 0, stream>>>(Qp, Kp, kvf, cs, alphaP, pq, pk);

  // 7. A = pq @ pk^T, causal-masked, bf16 (overwrites kv region).
  //    Fully-masked block (x=1,y=0) skipped: 3 xy-blocks per batch.
  gemm_bt<2><<<dim3(3, 1, 64), 256, 0, stream>>>(
      pq, 256, 524288L, 65536L, pk, 256, 524288L, 65536L, (void*)Ab, 256,
      524288L, 65536L, 256, 8, nullptr, 0, nullptr, nullptr);

  // 8. den = masked rowsum(A), clamped
  den_kernel<<<4096, 256, 0, stream>>>(Ab, den);

  // 9. V transpose per (b,h): Vt[d,j] = V[j,d]
  vtrans_kernel<<<dim3(8, 8, 64), dim3(32, 8), 0, stream>>>(Vp, Vt);

  // 10. attn = (A @ V) / den, K clamped causally, written into (B*L, D)
  gemm_bt<3><<<dim3(2, 2, 64), 256, 0, stream>>>(
      Ab, 256, 524288L, 65536L, Vt, 256, 524288L, 65536L, (void*)attnb, 2048,
      524288L, 256L, 256, 8, den, 256, nullptr, nullptr);

  // 11. x = attn @ Wo^T + bo + query (fp32)
  gemm_bt<4><<<dim3(16, 16, 1), 256, 0, stream>>>(
      attnb, 2048, 0L, 0L, Wob, 2048, 0L, 0L, (void*)x, 2048, 0L, 0L, 2048, 1,
      nullptr, 0, bo, query);

  // 12. LayerNorm -> d_out
  ln_kernel<<<2048, 256, 0, stream>>>(x, ln_g, ln_b, (float*)d_out);
}

// Round 4
// 345.747 us; speedup vs baseline: 1.0343x; 1.0139x over previous
//
#include <hip/hip_runtime.h>
#include <hip/hip_bf16.h>

using u16 = unsigned short;

typedef __bf16 bf16x8 __attribute__((ext_vector_type(8)));
typedef float  f32x4  __attribute__((ext_vector_type(4)));

__device__ __forceinline__ float b2f(u16 u) {
  union { unsigned u; float f; } v; v.u = ((unsigned)u) << 16; return v.f;
}
__device__ __forceinline__ u16 f2b(float f) {
  union { float f; unsigned u; } v; v.f = f;
  unsigned r = v.u + 0x7fffu + ((v.u >> 16) & 1u);
  return (u16)(r >> 16);
}

// async global->LDS, 16B per lane. LDS dest must be uniform base + lane*16.
__device__ __forceinline__ void gld_lds16(const void* g, void* l) {
  __builtin_amdgcn_global_load_lds(
      (__attribute__((address_space(1))) void*)(unsigned long long)(g),
      (__attribute__((address_space(3))) void*)(unsigned long long)(l),
      16, 0, 0);
}

// ---------------------------------------------------------------------------
// Generic NT GEMM: C[m,n] = sum_k A[m,k] * B[n,k], bf16 in, fp32 acc.
// Block tile 128x128, 4 waves (2x2), wave = 4x4 of 16x16x32 MFMA, BK=64
// (32 KB LDS; halves barrier-drain events vs BK=32, 32 MFMA per barrier).
// LDS row = 64 elems (128 B). XOR swizzle: physical granule g of row r holds
// global k-chunk g^(r&7); fragment ds_read_b128 at ((kk*4+quad)^(laneM&7))*8
// -> 2-way bank aliasing (free, m136).
// Batch via blockIdx.z: zb=z/HDIV, zh=z%HDIV; operand offset = zb*s1 + zh*s2.
// EPI: 0 = write bf16; 1 = write fp32;
//      2 = causal A-GEMM: grid x in {0,1,2} remapped to (bx,by) in
//          {(0,0),(0,1),(1,1)}, mask col<=row -> bf16;
//      3 = A@V: K clamped to (by+1)*128; den = masked rowsum(A) computed
//          from A-fragments in-register (shfl + LDS broadcast); write
//          bf16 of v/den;
//      4 = split-K Wo: zb==0 writes v+bias[col]+resid, zb==1 writes v (fp32)
//          NOTE: zb=1 destination = Cv + sC1 (sC1 may be NEGATIVE to land in
//          a different workspace region; keep it matching kernel_launch!)
// ---------------------------------------------------------------------------
template <int EPI>
__global__ __launch_bounds__(256) void gemm_bt(
    const u16* __restrict__ A, int lda, long sA1, long sA2,
    const u16* __restrict__ B, int ldb, long sB1, long sB2,
    void* __restrict__ Cv, int ldc, long sC1, long sC2,
    int K, int HDIV,
    const float* __restrict__ bias, const float* __restrict__ resid) {
  __shared__ __align__(16) u16 lds[16384];  // A:[0,8192) B:[8192,16384)
  __shared__ float denS[128];
  const int t = threadIdx.x;
  const int lane = t & 63;
  const int wave = t >> 6;
  const int wm = wave >> 1, wn = wave & 1;
  const int laneM = lane & 15, quad = lane >> 4;
  const int zb = blockIdx.z / HDIV, zh = blockIdx.z % HDIV;

  int bx = blockIdx.x, by = blockIdx.y;
  if (EPI == 2) { by = (bx >= 1) ? 1 : 0; bx = (bx == 2) ? 1 : 0; }
  const int kEnd = (EPI == 3) ? ((by + 1) * 128 < K ? (by + 1) * 128 : K) : K;

  const u16* Abase = A + zb * sA1 + zh * sA2 + (long)by * 128 * lda;
  const u16* Bbase = B + zb * sB1 + zh * sB2 + (long)bx * 128 * ldb;

  const int sRow = t >> 3;                    // staging row 0..31 (+32p)
  const int sc = ((t & 7) ^ (sRow & 7)) * 8;  // swizzled global chunk (elems)

  f32x4 acc[4][4];
#pragma unroll
  for (int i = 0; i < 4; ++i)
#pragma unroll
    for (int j = 0; j < 4; ++j) acc[i][j] = (f32x4){0.f, 0.f, 0.f, 0.f};
  float dsum[4] = {0.f, 0.f, 0.f, 0.f};

  const int fragA = (wm * 64 + laneM) * 64;  // + i*1024 + perm*8
  const int fragB = 8192 + (wn * 64 + laneM) * 64;
  const int pbase = laneM & 7;  // perm = (kk*4+quad) ^ pbase

  for (int k0 = 0; k0 < kEnd; k0 += 64) {
#pragma unroll
    for (int p = 0; p < 4; ++p)
      gld_lds16(Abase + (long)(p * 32 + sRow) * lda + k0 + sc,
                &lds[p * 2048 + t * 8]);
#pragma unroll
    for (int p = 0; p < 4; ++p)
      gld_lds16(Bbase + (long)(p * 32 + sRow) * ldb + k0 + sc,
                &lds[8192 + p * 2048 + t * 8]);
    __syncthreads();  // drains vmcnt(0): LDS staging complete
    bf16x8 af[2][4], bfv[2][4];
#pragma unroll
    for (int kk = 0; kk < 2; ++kk) {
      const int perm8 = ((kk * 4 + quad) ^ pbase) * 8;
#pragma unroll
      for (int i = 0; i < 4; ++i) {
        af[kk][i] = *(const bf16x8*)&lds[fragA + i * 1024 + perm8];
        bfv[kk][i] = *(const bf16x8*)&lds[fragB + i * 1024 + perm8];
      }
    }
    if (EPI == 3) {  // masked rowsum of A from fragments (den)
#pragma unroll
      for (int kk = 0; kk < 2; ++kk)
#pragma unroll
        for (int i = 0; i < 4; ++i) {
          union { bf16x8 v; u16 s[8]; } u; u.v = af[kk][i];
          float ds = 0.f;
#pragma unroll
          for (int e = 0; e < 8; ++e) ds += b2f(u.s[e]);
          dsum[i] += ds;
        }
    }
#pragma unroll
    for (int kk = 0; kk < 2; ++kk)
#pragma unroll
      for (int i = 0; i < 4; ++i)
#pragma unroll
        for (int j = 0; j < 4; ++j)
          acc[i][j] = __builtin_amdgcn_mfma_f32_16x16x32_bf16(
              af[kk][i], bfv[kk][j], acc[i][j], 0, 0, 0);
    __syncthreads();  // all waves done reading before next stage
  }

  if (EPI == 3) {
#pragma unroll
    for (int i = 0; i < 4; ++i) {
      float s = dsum[i];
      s += __shfl_xor(s, 16);
      s += __shfl_xor(s, 32);
      if (wn == 0 && quad == 0)
        denS[wm * 64 + i * 16 + laneM] = fmaxf(s, 1e-8f);
    }
    __syncthreads();
  }

  const long cOff = zb * sC1 + zh * sC2;
  const int colB = bx * 128 + wn * 64;
#pragma unroll
  for (int i = 0; i < 4; ++i) {
#pragma unroll
    for (int j = 0; j < 4; ++j) {
#pragma unroll
      for (int r = 0; r < 4; ++r) {
        const int lrow = wm * 64 + i * 16 + quad * 4 + r;  // row within block
        const int row = by * 128 + lrow;                   // within-batch row
        const int col = colB + j * 16 + laneM;             // within-batch col
        const long idx = cOff + (long)row * ldc + col;
        float v = acc[i][j][r];
        if (EPI == 0) {
          ((u16*)Cv)[idx] = f2b(v);
        } else if (EPI == 1) {
          ((float*)Cv)[idx] = v;
        } else if (EPI == 2) {
          ((u16*)Cv)[idx] = f2b(col <= row ? v : 0.0f);
        } else if (EPI == 3) {
          ((u16*)Cv)[idx] = f2b(v / denS[lrow]);
        } else {
          ((float*)Cv)[idx] =
              (zb == 0) ? v + bias[col] + resid[(long)row * ldc + col] : v;
        }
      }
    }
  }
}

// ---------------------------------------------------------------------------
// Convert 7 fp32 2048x2048 tensors -> bf16, dsts contiguous from dst base.
// ---------------------------------------------------------------------------
__global__ __launch_bounds__(256) void convert7(
    const float* __restrict__ s0, const float* __restrict__ s1,
    const float* __restrict__ s2, const float* __restrict__ s3,
    const float* __restrict__ s4, const float* __restrict__ s5,
    const float* __restrict__ s6, u16* __restrict__ dst) {
  long idx = (long)blockIdx.x * 256 + threadIdx.x;  // 0 .. 7*1048576-1
  int seg = (int)(idx >> 20);
  long off = (idx & 1048575) << 2;
  const float* s;
  switch (seg) {
    case 0: s = s0; break; case 1: s = s1; break; case 2: s = s2; break;
    case 3: s = s3; break; case 4: s = s4; break; case 5: s = s5; break;
    default: s = s6;
  }
  float4 v = *(const float4*)(s + off);
  ushort4 o;
  o.x = f2b(v.x); o.y = f2b(v.y); o.z = f2b(v.z); o.w = f2b(v.w);
  *(ushort4*)(dst + (long)seg * 4194304 + off) = o;
}

// ---------------------------------------------------------------------------
// partial[h,chunk,m] = sum over 128 (b,l) rows of kv[b,h,l,m]
// ---------------------------------------------------------------------------
__global__ __launch_bounds__(256) void kv_mean_partial(
    const float* __restrict__ kv, float* __restrict__ part) {
  int h = blockIdx.x, chunk = blockIdx.y, m = threadIdx.x;
  float acc = 0.f;
  for (int g = chunk * 128; g < chunk * 128 + 128; ++g) {
    int b = g >> 8, l = g & 255;
    acc += kv[(((long)(b * 8 + h) * 256) + l) * 256 + m];
  }
  part[(h * 16 + chunk) * 256 + m] = acc;
}

// cs_seq[h,m]: scan over heads collecting the PRE-update carry.
__global__ __launch_bounds__(256) void cs_kernel(
    const float* __restrict__ part, float* __restrict__ cs,
    const float* __restrict__ alphaP, const float* __restrict__ betaP) {
  int m = threadIdx.x;
  float alpha = *alphaP, beta = *betaP;
  float c = 0.f;
  for (int h = 0; h < 8; ++h) {
    cs[h * 256 + m] = c;
    float s = 0.f;
    for (int ch = 0; ch < 16; ++ch) s += part[(h * 16 + ch) * 256 + m];
    c = beta * c + alpha * (s * (1.0f / 2048.0f));
  }
}

// pq = phi(Q * (cs + alpha*(kv - cs))), pk = phi(K); phi(x)=x>0?x+1:exp(x)
__global__ __launch_bounds__(256) void pqpk_kernel(
    const u16* __restrict__ Qp, const u16* __restrict__ Kp,
    const float* __restrict__ kv, const float* __restrict__ cs,
    const float* __restrict__ alphaP, u16* __restrict__ pq,
    u16* __restrict__ pk) {
  long idx = (long)blockIdx.x * 256 + threadIdx.x;  // (b,h,l,d) packed
  int d = idx & 255, l = (int)((idx >> 8) & 255), h = (int)((idx >> 16) & 7),
      b = (int)(idx >> 19);
  float alpha = *alphaP;
  long pidx = ((long)(b * 256 + l)) * 2048 + h * 256 + d;
  float Qv = b2f(Qp[pidx]);
  float kvv = kv[idx];  // kv layout (b,h,l,m) == idx packing
  float csv = cs[h * 256 + d];
  float qm = Qv * (csv + alpha * (kvv - csv));
  pq[idx] = f2b(qm > 0.f ? qm + 1.f : expf(qm));
  float Kv = b2f(Kp[pidx]);
  pk[idx] = f2b(Kv > 0.f ? Kv + 1.f : expf(Kv));
}

// Vt[b,h,d,j] = V[b*256+j, h*256+d]  (per-(b,h) 256x256 transpose)
__global__ __launch_bounds__(256) void vtrans_kernel(const u16* __restrict__ Vp,
                                                     u16* __restrict__ Vt) {
  __shared__ u16 tile[32][33];
  int z = blockIdx.z, b = z >> 3, h = z & 7;
  int jT = blockIdx.x * 32, dT = blockIdx.y * 32;
  int tx = threadIdx.x, ty = threadIdx.y;  // (32, 8)
#pragma unroll
  for (int ii = 0; ii < 4; ++ii) {
    int j = jT + ty + ii * 8, d = dT + tx;
    tile[ty + ii * 8][tx] = Vp[(long)(b * 256 + j) * 2048 + h * 256 + d];
  }
  __syncthreads();
#pragma unroll
  for (int ii = 0; ii < 4; ++ii) {
    int d = dT + ty + ii * 8, j = jT + tx;
    Vt[(long)z * 65536 + d * 256 + j] = tile[tx][ty + ii * 8];
  }
}

// LayerNorm over rows of 2048; input = x0 + x1 (split-K partials).
__global__ __launch_bounds__(256) void ln_kernel(
    const float* __restrict__ x0, const float* __restrict__ x1,
    const float* __restrict__ g, const float* __restrict__ bb,
    float* __restrict__ out) {
  int row = blockIdx.x, t = threadIdx.x;
  const float4* xr0 = (const float4*)(x0 + (long)row * 2048);
  const float4* xr1 = (const float4*)(x1 + (long)row * 2048);
  float4 a0 = xr0[t], b0 = xr1[t], a1 = xr0[t + 256], b1 = xr1[t + 256];
  float4 v0, v1;
  v0.x = a0.x + b0.x; v0.y = a0.y + b0.y; v0.z = a0.z + b0.z; v0.w = a0.w + b0.w;
  v1.x = a1.x + b1.x; v1.y = a1.y + b1.y; v1.z = a1.z + b1.z; v1.w = a1.w + b1.w;
  float s = v0.x + v0.y + v0.z + v0.w + v1.x + v1.y + v1.z + v1.w;
  float ss = v0.x * v0.x + v0.y * v0.y + v0.z * v0.z + v0.w * v0.w +
             v1.x * v1.x + v1.y * v1.y + v1.z * v1.z + v1.w * v1.w;
  for (int o = 32; o; o >>= 1) { s += __shfl_xor(s, o); ss += __shfl_xor(ss, o); }
  __shared__ float a1s[4], a2s[4];
  int wave = t >> 6, lane = t & 63;
  if (lane == 0) { a1s[wave] = s; a2s[wave] = ss; }
  __syncthreads();
  s = a1s[0] + a1s[1] + a1s[2] + a1s[3];
  ss = a2s[0] + a2s[1] + a2s[2] + a2s[3];
  float mu = s * (1.f / 2048.f);
  float var = ss * (1.f / 2048.f) - mu * mu;
  float rstd = rsqrtf(var + 1e-5f);
  const float4* g4 = (const float4*)g;
  const float4* b4 = (const float4*)bb;
  float4* orow = (float4*)(out + (long)row * 2048);
  float4 gg = g4[t], bv = b4[t], r;
  r.x = (v0.x - mu) * rstd * gg.x + bv.x;
  r.y = (v0.y - mu) * rstd * gg.y + bv.y;
  r.z = (v0.z - mu) * rstd * gg.z + bv.z;
  r.w = (v0.w - mu) * rstd * gg.w + bv.w;
  orow[t] = r;
  gg = g4[t + 256]; bv = b4[t + 256];
  r.x = (v1.x - mu) * rstd * gg.x + bv.x;
  r.y = (v1.y - mu) * rstd * gg.y + bv.y;
  r.z = (v1.z - mu) * rstd * gg.z + bv.z;
  r.w = (v1.w - mu) * rstd * gg.w + bv.w;
  orow[t + 256] = r;
}

extern "C" void kernel_launch(void* const* d_in, const int* in_sizes, int n_in,
                              void* d_out, int out_size, void* d_ws,
                              size_t ws_size, hipStream_t stream) {
  const float* query = (const float*)d_in[0];
  const float* key = (const float*)d_in[1];
  const float* value = (const float*)d_in[2];
  const float* Wq = (const float*)d_in[3];
  const float* Wk = (const float*)d_in[4];
  const float* Wv = (const float*)d_in[5];
  const float* Wo = (const float*)d_in[6];
  const float* bo = (const float*)d_in[7];
  const float* ln_g = (const float*)d_in[8];
  const float* ln_b = (const float*)d_in[9];
  const float* alphaP = (const float*)d_in[10];
  const float* betaP = (const float*)d_in[11];

  char* ws = (char*)d_ws;
  const long SZ = 8388608;  // bytes of one 2048x2048 bf16 tensor
  u16* qb = (u16*)(ws);                // q,k,v bf16 (3*SZ); x1 aliases later
  u16* Wb = (u16*)(ws + 3 * SZ);       // Wq,Wk,Wv,Wo bf16 (4*SZ)
  u16* Qp = (u16*)(ws + 7 * SZ);       // Q,K,V projections bf16 (3*SZ)
  float* kvf = (float*)(ws + 10 * SZ); // kv fp32 (2*SZ); later aliased by Ab
  u16* pq = (u16*)(ws + 12 * SZ);      // (SZ)
  u16* pk = (u16*)(ws + 13 * SZ);      // (SZ)
  u16* Vt = (u16*)(ws + 14 * SZ);      // (SZ)
  u16* attnb = (u16*)(ws + 15 * SZ);   // (SZ)
  u16* Ab = (u16*)(ws + 10 * SZ);      // aliases kvf (dead after pqpk)
  float* x0 = (float*)(ws + 12 * SZ);  // 16MB, aliases pq/pk (dead after A GEMM)
  float* x1 = (float*)(ws);            // 16MB, aliases qb..vb (dead after proj)
  float* part = (float*)(ws + 16 * SZ);            // 16 KB
  float* cs = (float*)(ws + 16 * SZ + 16384);      // 8 KB

  u16* Kp = Qp + 4194304;
  u16* Vp = Qp + 8388608;
  u16* Wob = Wb + 3 * 4194304;

  // 1. fp32 -> bf16 converts (7 tensors)
  convert7<<<28672, 256, 0, stream>>>(query, key, value, Wq, Wk, Wv, Wo, qb);

  // 2. Q/K/V projections: z=0..2 batched, C[m,n] = sum_k x[m,k] W[n,k]
  gemm_bt<0><<<dim3(16, 16, 3), 256, 0, stream>>>(
      qb, 2048, 4194304L, 0L, Wb, 2048, 4194304L, 0L, (void*)Qp, 2048,
      4194304L, 0L, 2048, 1, nullptr, nullptr);

  // 3. kv[b,h,l,m] = sum_d K[b,h,l,d] V[b,h,m,d]  (64 batches, fp32 out)
  gemm_bt<1><<<dim3(2, 2, 64), 256, 0, stream>>>(
      Kp, 2048, 524288L, 256L, Vp, 2048, 524288L, 256L, (void*)kvf, 256,
      524288L, 65536L, 256, 8, nullptr, nullptr);

  // 4-5. head-means of kv + cs scan over heads
  kv_mean_partial<<<dim3(8, 16), 256, 0, stream>>>(kvf, part);
  cs_kernel<<<1, 256, 0, stream>>>(part, cs, alphaP, betaP);

  // 6. pq = phi(Q*(cs+alpha*(kv-cs))), pk = phi(K)
  pqpk_kernel<<<16384, 256, 0, stream>>>(Qp, Kp, kvf, cs, alphaP, pq, pk);

  // 7. A = pq @ pk^T, causal-masked, bf16 (overwrites kv region).
  //    Fully-masked block (x=1,y=0) skipped: 3 xy-blocks per batch.
  gemm_bt<2><<<dim3(3, 1, 64), 256, 0, stream>>>(
      pq, 256, 524288L, 65536L, pk, 256, 524288L, 65536L, (void*)Ab, 256,
      524288L, 65536L, 256, 8, nullptr, nullptr);

  // 8. V transpose per (b,h): Vt[d,j] = V[j,d]
  vtrans_kernel<<<dim3(8, 8, 64), dim3(32, 8), 0, stream>>>(Vp, Vt);

  // 9. attn = (A @ V) / den, den fused from A-fragments, K clamped causally
  gemm_bt<3><<<dim3(2, 2, 64), 256, 0, stream>>>(
      Ab, 256, 524288L, 65536L, Vt, 256, 524288L, 65536L, (void*)attnb, 2048,
      524288L, 256L, 256, 8, nullptr, nullptr);

  // 10. x = attn @ Wo^T (+ bo + query on z=0), split-K=2.
  //     sC1 = x1 - x0 = -12*SZ/4 floats: zb=0 -> x0 (ws+12SZ), zb=1 -> x1 (ws).
  gemm_bt<4><<<dim3(16, 16, 2), 256, 0, stream>>>(
      attnb, 2048, 1024L, 0L, Wob, 2048, 1024L, 0L, (void*)x0, 2048,
      -25165824L, 0L, 1024, 1, bo, query);

  // 11. LayerNorm(x0 + x1) -> d_out
  ln_kernel<<<2048, 256, 0, stream>>>(x0, x1, ln_g, ln_b, (float*)d_out);
}

// Round 5
// 331.971 us; speedup vs baseline: 1.0772x; 1.0415x over previous
//
#include <hip/hip_runtime.h>
#include <hip/hip_bf16.h>

using u16 = unsigned short;

typedef __bf16 bf16x8 __attribute__((ext_vector_type(8)));
typedef float  f32x4  __attribute__((ext_vector_type(4)));

__device__ __forceinline__ float b2f(u16 u) {
  union { unsigned u; float f; } v; v.u = ((unsigned)u) << 16; return v.f;
}
__device__ __forceinline__ u16 f2b(float f) {
  union { float f; unsigned u; } v; v.f = f;
  unsigned r = v.u + 0x7fffu + ((v.u >> 16) & 1u);
  return (u16)(r >> 16);
}

// async global->LDS, 16B per lane. LDS dest must be uniform base + lane*16.
__device__ __forceinline__ void gld_lds16(const void* g, void* l) {
  __builtin_amdgcn_global_load_lds(
      (__attribute__((address_space(1))) void*)(unsigned long long)(g),
      (__attribute__((address_space(3))) void*)(unsigned long long)(l),
      16, 0, 0);
}

// ---------------------------------------------------------------------------
// Generic NT GEMM: C[m,n] = sum_k A[m,k] * B[n,k], bf16 in, fp32 acc.
// Block tile 128x128, 4 waves (2x2), wave = 4x4 of 16x16x32 MFMA.
// BK template param:
//   BK=32 (16 KB LDS, 72 VGPR) for occupancy-sensitive big-grid GEMMs
//     (proj 768 blocks, Wo 512 blocks) — R4 showed BK=64 halves occupancy
//     there (27.8%->15.8%) and costs 11%.
//   BK=64 (32 KB LDS) for grid-limited 1-block/CU GEMMs (kv/A/AV, <=256
//     blocks) where fewer barrier drains is free.
// XOR swizzle keeps ds_read_b128 at 2-way bank aliasing (free, m136):
//   BK=64: granule g of row r holds chunk g^(r&7); read perm (kk*4+quad)^(laneM&7)
//   BK=32: granule g of row r holds chunk g^((r>>1)&3); read perm quad^((laneM>>1)&3)
// Batch via blockIdx.z: zb=z/HDIV, zh=z%HDIV; operand offset = zb*s1 + zh*s2.
// EPI: 0 = write bf16;
//      1 = kv GEMM: write bf16 AND atomicAdd per-column tile sums into
//          partOut[zh*256 + col] (cs head-mean fusion; partOut pre-zeroed);
//      2 = causal A-GEMM: grid x in {0,1,2} remapped to (bx,by) in
//          {(0,0),(0,1),(1,1)}, mask col<=row -> bf16;
//      3 = A@V: K clamped to (by+1)*128; den = rowsum(A) from A-fragments
//          in-register (shfl + LDS broadcast); write bf16 of v/den;
//      4 = split-K Wo: zb==0 writes v+bias[col]+resid, zb==1 writes v (fp32)
//          zb=1 dest = Cv + sC1 (may be negative; must match kernel_launch!)
// ---------------------------------------------------------------------------
template <int EPI, int BK>
__global__ __launch_bounds__(256) void gemm_bt(
    const u16* __restrict__ A, int lda, long sA1, long sA2,
    const u16* __restrict__ B, int ldb, long sB1, long sB2,
    void* __restrict__ Cv, int ldc, long sC1, long sC2,
    int K, int HDIV,
    const float* __restrict__ bias, const float* __restrict__ resid,
    float* __restrict__ partOut) {
  __shared__ __align__(16) u16 lds[2 * 128 * BK];
  __shared__ float denS[128];
  const int t = threadIdx.x;
  const int lane = t & 63;
  const int wave = t >> 6;
  const int wm = wave >> 1, wn = wave & 1;
  const int laneM = lane & 15, quad = lane >> 4;
  const int zb = blockIdx.z / HDIV, zh = blockIdx.z % HDIV;

  int bx = blockIdx.x, by = blockIdx.y;
  if (EPI == 2) { by = (bx >= 1) ? 1 : 0; bx = (bx == 2) ? 1 : 0; }
  const int kEnd = (EPI == 3) ? ((by + 1) * 128 < K ? (by + 1) * 128 : K) : K;

  const u16* Abase = A + zb * sA1 + zh * sA2 + (long)by * 128 * lda;
  const u16* Bbase = B + zb * sB1 + zh * sB2 + (long)bx * 128 * ldb;

  constexpr int STEPS = BK / 16;   // staging steps per operand (2048 elem each)
  constexpr int RPS = 2048 / BK;   // rows per staging step
  constexpr int KK = BK / 32;      // MFMA k-steps per LDS tile
  const int sRow = (BK == 64) ? (t >> 3) : (t >> 2);
  const int sg = (BK == 64) ? (t & 7) : (t & 3);
  const int swz = (BK == 64) ? (sg ^ (sRow & 7)) : (sg ^ ((sRow >> 1) & 3));
  const int sc = swz * 8;  // swizzled global k-chunk offset (elems)

  f32x4 acc[4][4];
#pragma unroll
  for (int i = 0; i < 4; ++i)
#pragma unroll
    for (int j = 0; j < 4; ++j) acc[i][j] = (f32x4){0.f, 0.f, 0.f, 0.f};
  float dsum[4] = {0.f, 0.f, 0.f, 0.f};

  for (int k0 = 0; k0 < kEnd; k0 += BK) {
#pragma unroll
    for (int p = 0; p < STEPS; ++p)
      gld_lds16(Abase + (long)(p * RPS + sRow) * lda + k0 + sc,
                &lds[p * 2048 + t * 8]);
#pragma unroll
    for (int p = 0; p < STEPS; ++p)
      gld_lds16(Bbase + (long)(p * RPS + sRow) * ldb + k0 + sc,
                &lds[128 * BK + p * 2048 + t * 8]);
    __syncthreads();  // drains vmcnt(0): LDS staging complete
    bf16x8 af[KK][4], bfv[KK][4];
#pragma unroll
    for (int kk = 0; kk < KK; ++kk) {
      int perm8;
      if (BK == 64) perm8 = ((kk * 4 + quad) ^ (laneM & 7)) * 8;
      else          perm8 = (quad ^ ((laneM >> 1) & 3)) * 8;
#pragma unroll
      for (int i = 0; i < 4; ++i) {
        af[kk][i] = *(const bf16x8*)&lds[(wm * 64 + i * 16 + laneM) * BK + perm8];
        bfv[kk][i] =
            *(const bf16x8*)&lds[128 * BK + (wn * 64 + i * 16 + laneM) * BK + perm8];
      }
    }
    if (EPI == 3) {  // rowsum of A from fragments (den; mask is pre-applied)
#pragma unroll
      for (int kk = 0; kk < KK; ++kk)
#pragma unroll
        for (int i = 0; i < 4; ++i) {
          union { bf16x8 v; u16 s[8]; } u; u.v = af[kk][i];
          float ds = 0.f;
#pragma unroll
          for (int e = 0; e < 8; ++e) ds += b2f(u.s[e]);
          dsum[i] += ds;
        }
    }
#pragma unroll
    for (int kk = 0; kk < KK; ++kk)
#pragma unroll
      for (int i = 0; i < 4; ++i)
#pragma unroll
        for (int j = 0; j < 4; ++j)
          acc[i][j] = __builtin_amdgcn_mfma_f32_16x16x32_bf16(
              af[kk][i], bfv[kk][j], acc[i][j], 0, 0, 0);
    __syncthreads();  // all waves done reading before next stage
  }

  if (EPI == 3) {
#pragma unroll
    for (int i = 0; i < 4; ++i) {
      float s = dsum[i];
      s += __shfl_xor(s, 16);
      s += __shfl_xor(s, 32);
      if (wn == 0 && quad == 0)
        denS[wm * 64 + i * 16 + laneM] = fmaxf(s, 1e-8f);
    }
    __syncthreads();
  }

  if (EPI == 1) {  // column sums of tile -> part[zh*256 + col] (cs fusion)
#pragma unroll
    for (int j = 0; j < 4; ++j) {
      float s = 0.f;
#pragma unroll
      for (int i = 0; i < 4; ++i)
#pragma unroll
        for (int r = 0; r < 4; ++r) s += acc[i][j][r];
      s += __shfl_xor(s, 16);
      s += __shfl_xor(s, 32);
      if (quad == 0)
        atomicAdd(&partOut[zh * 256 + bx * 128 + wn * 64 + j * 16 + laneM], s);
    }
  }

  const long cOff = zb * sC1 + zh * sC2;
  const int colB = bx * 128 + wn * 64;
#pragma unroll
  for (int i = 0; i < 4; ++i) {
#pragma unroll
    for (int j = 0; j < 4; ++j) {
#pragma unroll
      for (int r = 0; r < 4; ++r) {
        const int lrow = wm * 64 + i * 16 + quad * 4 + r;  // row within block
        const int row = by * 128 + lrow;                   // within-batch row
        const int col = colB + j * 16 + laneM;             // within-batch col
        const long idx = cOff + (long)row * ldc + col;
        float v = acc[i][j][r];
        if (EPI == 0 || EPI == 1) {
          ((u16*)Cv)[idx] = f2b(v);
        } else if (EPI == 2) {
          ((u16*)Cv)[idx] = f2b(col <= row ? v : 0.0f);
        } else if (EPI == 3) {
          ((u16*)Cv)[idx] = f2b(v / denS[lrow]);
        } else {
          ((float*)Cv)[idx] =
              (zb == 0) ? v + bias[col] + resid[(long)row * ldc + col] : v;
        }
      }
    }
  }
}

// ---------------------------------------------------------------------------
// Convert 7 fp32 2048x2048 tensors -> bf16, dsts contiguous from dst base.
// ---------------------------------------------------------------------------
__global__ __launch_bounds__(256) void convert7(
    const float* __restrict__ s0, const float* __restrict__ s1,
    const float* __restrict__ s2, const float* __restrict__ s3,
    const float* __restrict__ s4, const float* __restrict__ s5,
    const float* __restrict__ s6, u16* __restrict__ dst) {
  long idx = (long)blockIdx.x * 256 + threadIdx.x;  // 0 .. 7*1048576-1
  int seg = (int)(idx >> 20);
  long off = (idx & 1048575) << 2;
  const float* s;
  switch (seg) {
    case 0: s = s0; break; case 1: s = s1; break; case 2: s = s2; break;
    case 3: s = s3; break; case 4: s = s4; break; case 5: s = s5; break;
    default: s = s6;
  }
  float4 v = *(const float4*)(s + off);
  ushort4 o;
  o.x = f2b(v.x); o.y = f2b(v.y); o.z = f2b(v.z); o.w = f2b(v.w);
  *(ushort4*)(dst + (long)seg * 4194304 + off) = o;
}

// cs_seq[h,m]: scan over heads collecting the PRE-update carry.
// part[h*256+m] holds sum over (b,l) of kv (from GEMM-epilogue atomics).
__global__ __launch_bounds__(256) void cs_kernel(
    const float* __restrict__ part, float* __restrict__ cs,
    const float* __restrict__ alphaP, const float* __restrict__ betaP) {
  int m = threadIdx.x;
  float alpha = *alphaP, beta = *betaP;
  float c = 0.f;
  for (int h = 0; h < 8; ++h) {
    cs[h * 256 + m] = c;
    c = beta * c + alpha * (part[h * 256 + m] * (1.0f / 2048.0f));
  }
}

// pq = phi(Q * (cs + alpha*(kv - cs))), pk = phi(K); phi(x)=x>0?x+1:exp(x)
__global__ __launch_bounds__(256) void pqpk_kernel(
    const u16* __restrict__ Qp, const u16* __restrict__ Kp,
    const u16* __restrict__ kv, const float* __restrict__ cs,
    const float* __restrict__ alphaP, u16* __restrict__ pq,
    u16* __restrict__ pk) {
  long idx = (long)blockIdx.x * 256 + threadIdx.x;  // (b,h,l,d) packed
  int d = idx & 255, l = (int)((idx >> 8) & 255), h = (int)((idx >> 16) & 7),
      b = (int)(idx >> 19);
  float alpha = *alphaP;
  long pidx = ((long)(b * 256 + l)) * 2048 + h * 256 + d;
  float Qv = b2f(Qp[pidx]);
  float kvv = b2f(kv[idx]);  // kv layout (b,h,l,m) == idx packing
  float csv = cs[h * 256 + d];
  float qm = Qv * (csv + alpha * (kvv - csv));
  pq[idx] = f2b(qm > 0.f ? qm + 1.f : expf(qm));
  float Kv = b2f(Kp[pidx]);
  pk[idx] = f2b(Kv > 0.f ? Kv + 1.f : expf(Kv));
}

// Vt[b,h,d,j] = V[b*256+j, h*256+d]  (per-(b,h) 256x256 transpose)
__global__ __launch_bounds__(256) void vtrans_kernel(const u16* __restrict__ Vp,
                                                     u16* __restrict__ Vt) {
  __shared__ u16 tile[32][33];
  int z = blockIdx.z, b = z >> 3, h = z & 7;
  int jT = blockIdx.x * 32, dT = blockIdx.y * 32;
  int tx = threadIdx.x, ty = threadIdx.y;  // (32, 8)
#pragma unroll
  for (int ii = 0; ii < 4; ++ii) {
    int j = jT + ty + ii * 8, d = dT + tx;
    tile[ty + ii * 8][tx] = Vp[(long)(b * 256 + j) * 2048 + h * 256 + d];
  }
  __syncthreads();
#pragma unroll
  for (int ii = 0; ii < 4; ++ii) {
    int d = dT + ty + ii * 8, j = jT + tx;
    Vt[(long)z * 65536 + d * 256 + j] = tile[tx][ty + ii * 8];
  }
}

// LayerNorm over rows of 2048; input = x0 + x1 (split-K partials).
__global__ __launch_bounds__(256) void ln_kernel(
    const float* __restrict__ x0, const float* __restrict__ x1,
    const float* __restrict__ g, const float* __restrict__ bb,
    float* __restrict__ out) {
  int row = blockIdx.x, t = threadIdx.x;
  const float4* xr0 = (const float4*)(x0 + (long)row * 2048);
  const float4* xr1 = (const float4*)(x1 + (long)row * 2048);
  float4 a0 = xr0[t], b0 = xr1[t], a1 = xr0[t + 256], b1 = xr1[t + 256];
  float4 v0, v1;
  v0.x = a0.x + b0.x; v0.y = a0.y + b0.y; v0.z = a0.z + b0.z; v0.w = a0.w + b0.w;
  v1.x = a1.x + b1.x; v1.y = a1.y + b1.y; v1.z = a1.z + b1.z; v1.w = a1.w + b1.w;
  float s = v0.x + v0.y + v0.z + v0.w + v1.x + v1.y + v1.z + v1.w;
  float ss = v0.x * v0.x + v0.y * v0.y + v0.z * v0.z + v0.w * v0.w +
             v1.x * v1.x + v1.y * v1.y + v1.z * v1.z + v1.w * v1.w;
  for (int o = 32; o; o >>= 1) { s += __shfl_xor(s, o); ss += __shfl_xor(ss, o); }
  __shared__ float a1s[4], a2s[4];
  int wave = t >> 6, lane = t & 63;
  if (lane == 0) { a1s[wave] = s; a2s[wave] = ss; }
  __syncthreads();
  s = a1s[0] + a1s[1] + a1s[2] + a1s[3];
  ss = a2s[0] + a2s[1] + a2s[2] + a2s[3];
  float mu = s * (1.f / 2048.f);
  float var = ss * (1.f / 2048.f) - mu * mu;
  float rstd = rsqrtf(var + 1e-5f);
  const float4* g4 = (const float4*)g;
  const float4* b4 = (const float4*)bb;
  float4* orow = (float4*)(out + (long)row * 2048);
  float4 gg = g4[t], bv = b4[t], r;
  r.x = (v0.x - mu) * rstd * gg.x + bv.x;
  r.y = (v0.y - mu) * rstd * gg.y + bv.y;
  r.z = (v0.z - mu) * rstd * gg.z + bv.z;
  r.w = (v0.w - mu) * rstd * gg.w + bv.w;
  orow[t] = r;
  gg = g4[t + 256]; bv = b4[t + 256];
  r.x = (v1.x - mu) * rstd * gg.x + bv.x;
  r.y = (v1.y - mu) * rstd * gg.y + bv.y;
  r.z = (v1.z - mu) * rstd * gg.z + bv.z;
  r.w = (v1.w - mu) * rstd * gg.w + bv.w;
  orow[t + 256] = r;
}

extern "C" void kernel_launch(void* const* d_in, const int* in_sizes, int n_in,
                              void* d_out, int out_size, void* d_ws,
                              size_t ws_size, hipStream_t stream) {
  const float* query = (const float*)d_in[0];
  const float* key = (const float*)d_in[1];
  const float* value = (const float*)d_in[2];
  const float* Wq = (const float*)d_in[3];
  const float* Wk = (const float*)d_in[4];
  const float* Wv = (const float*)d_in[5];
  const float* Wo = (const float*)d_in[6];
  const float* bo = (const float*)d_in[7];
  const float* ln_g = (const float*)d_in[8];
  const float* ln_b = (const float*)d_in[9];
  const float* alphaP = (const float*)d_in[10];
  const float* betaP = (const float*)d_in[11];

  char* ws = (char*)d_ws;
  const long SZ = 8388608;  // bytes of one 2048x2048 bf16 tensor
  u16* qb = (u16*)(ws);                // q,k,v bf16 (3*SZ); x1 aliases later
  u16* Wb = (u16*)(ws + 3 * SZ);       // Wq,Wk,Wv,Wo bf16 (4*SZ)
  u16* Qp = (u16*)(ws + 7 * SZ);       // Q,K,V projections bf16 (3*SZ)
  u16* kvb = (u16*)(ws + 10 * SZ);     // kv bf16 (SZ); later aliased by Ab
  u16* pq = (u16*)(ws + 12 * SZ);      // (SZ)
  u16* pk = (u16*)(ws + 13 * SZ);      // (SZ)
  u16* Vt = (u16*)(ws + 14 * SZ);      // (SZ)
  u16* attnb = (u16*)(ws + 15 * SZ);   // (SZ)
  u16* Ab = (u16*)(ws + 10 * SZ);      // aliases kvb (dead after pqpk)
  float* x0 = (float*)(ws + 12 * SZ);  // 16MB, aliases pq/pk (dead after A GEMM)
  float* x1 = (float*)(ws);            // 16MB, aliases qb..vb (dead after proj)
  float* part = (float*)(ws + 16 * SZ);            // 8 KB (atomic-accumulated)
  float* cs = (float*)(ws + 16 * SZ + 16384);      // 8 KB

  u16* Kp = Qp + 4194304;
  u16* Vp = Qp + 8388608;
  u16* Wob = Wb + 3 * 4194304;

  // 0. zero the cs partial-sum accumulator (d_ws is re-poisoned every call)
  hipMemsetAsync(part, 0, 8 * 256 * sizeof(float), stream);

  // 1. fp32 -> bf16 converts (7 tensors)
  convert7<<<28672, 256, 0, stream>>>(query, key, value, Wq, Wk, Wv, Wo, qb);

  // 2. Q/K/V projections: z=0..2 batched, C[m,n] = sum_k x[m,k] W[n,k]
  gemm_bt<0, 32><<<dim3(16, 16, 3), 256, 0, stream>>>(
      qb, 2048, 4194304L, 0L, Wb, 2048, 4194304L, 0L, (void*)Qp, 2048,
      4194304L, 0L, 2048, 1, nullptr, nullptr, nullptr);

  // 3. kv[b,h,l,m] = sum_d K[b,h,l,d] V[b,h,m,d] (64 batches, bf16 out)
  //    + fused column sums into part[h*256+m] via atomics
  gemm_bt<1, 64><<<dim3(2, 2, 64), 256, 0, stream>>>(
      Kp, 2048, 524288L, 256L, Vp, 2048, 524288L, 256L, (void*)kvb, 256,
      524288L, 65536L, 256, 8, nullptr, nullptr, part);

  // 4. cs scan over heads (head-means already in part)
  cs_kernel<<<1, 256, 0, stream>>>(part, cs, alphaP, betaP);

  // 5. pq = phi(Q*(cs+alpha*(kv-cs))), pk = phi(K)
  pqpk_kernel<<<16384, 256, 0, stream>>>(Qp, Kp, kvb, cs, alphaP, pq, pk);

  // 6. A = pq @ pk^T, causal-masked, bf16 (overwrites kv region).
  //    Fully-masked block (x=1,y=0) skipped: 3 xy-blocks per batch.
  gemm_bt<2, 64><<<dim3(3, 1, 64), 256, 0, stream>>>(
      pq, 256, 524288L, 65536L, pk, 256, 524288L, 65536L, (void*)Ab, 256,
      524288L, 65536L, 256, 8, nullptr, nullptr, nullptr);

  // 7. V transpose per (b,h): Vt[d,j] = V[j,d]
  vtrans_kernel<<<dim3(8, 8, 64), dim3(32, 8), 0, stream>>>(Vp, Vt);

  // 8. attn = (A @ V) / den, den fused from A-fragments, K clamped causally
  gemm_bt<3, 64><<<dim3(2, 2, 64), 256, 0, stream>>>(
      Ab, 256, 524288L, 65536L, Vt, 256, 524288L, 65536L, (void*)attnb, 2048,
      524288L, 256L, 256, 8, nullptr, nullptr, nullptr);

  // 9. x = attn @ Wo^T (+ bo + query on z=0), split-K=2.
  //    sC1 = x1 - x0 = -12*SZ/4 floats: zb=0 -> x0 (ws+12SZ), zb=1 -> x1 (ws).
  gemm_bt<4, 32><<<dim3(16, 16, 2), 256, 0, stream>>>(
      attnb, 2048, 1024L, 0L, Wob, 2048, 1024L, 0L, (void*)x0, 2048,
      -25165824L, 0L, 1024, 1, bo, query, nullptr);

  // 10. LayerNorm(x0 + x1) -> d_out
  ln_kernel<<<2048, 256, 0, stream>>>(x0, x1, ln_g, ln_b, (float*)d_out);
}